// Round 1
// baseline (1033.538 us; speedup 1.0000x reference)
//
#include <hip/hip_runtime.h>
#include <stdint.h>

#define T_DIM 512
#define B_DIM 64
#define D_DIM 1024
#define H_DIM 8
#define DH_DIM 128
#define MROWS (T_DIM * B_DIM)   // 32768 rows across all timesteps

typedef unsigned short u16;
typedef __attribute__((ext_vector_type(8))) __bf16 bf16x8;
typedef __attribute__((ext_vector_type(4))) float f32x4;

__device__ __forceinline__ u16 f2bf(float f) {
  union { float f; uint32_t u; } v; v.f = f;
  uint32_t u = v.u;
  u += 0x7fffu + ((u >> 16) & 1u);   // RNE
  return (u16)(u >> 16);
}
__device__ __forceinline__ float bf2f(u16 h) {
  union { uint32_t u; float f; } v; v.u = ((uint32_t)h) << 16;
  return v.f;
}

__device__ __forceinline__ void gload16(const void* g, void* l) {
  __builtin_amdgcn_global_load_lds(
      (const __attribute__((address_space(1))) uint32_t*)g,
      (__attribute__((address_space(3))) uint32_t*)l, 16, 0, 0);
}

// ---------------- elementwise prep ----------------

__global__ void cast_bf16_kernel(const float* __restrict__ in, u16* __restrict__ out, size_t n8) {
  size_t i = (size_t)blockIdx.x * blockDim.x + threadIdx.x;
  const size_t stride = (size_t)gridDim.x * blockDim.x;
  for (; i < n8; i += stride) {
    const float4 a = ((const float4*)in)[i * 2];
    const float4 b = ((const float4*)in)[i * 2 + 1];
    union { u16 h[8]; uint4 u; } o;
    o.h[0] = f2bf(a.x); o.h[1] = f2bf(a.y); o.h[2] = f2bf(a.z); o.h[3] = f2bf(a.w);
    o.h[4] = f2bf(b.x); o.h[5] = f2bf(b.y); o.h[6] = f2bf(b.z); o.h[7] = f2bf(b.w);
    ((uint4*)out)[i] = o.u;
  }
}

// Wc[n][k] = Wr[n][k]+Wi[n][k] (k<1024)  |  Wr[n][k-1024]-Wi[n][k-1024]  -> (1024, 2048) bf16
__global__ void prep_wc_kernel(const float* __restrict__ Wr, const float* __restrict__ Wi,
                               u16* __restrict__ Wc) {
  const int idx = blockIdx.x * 256 + threadIdx.x;  // over 1024*2048
  const int n = idx >> 11;
  const int k = idx & 2047;
  const int kk = k & 1023;
  const float a = Wr[n * 1024 + kk], b = Wi[n * 1024 + kk];
  Wc[idx] = f2bf(k < 1024 ? a + b : a - b);
}

__global__ void prep_bc_kernel(const float* __restrict__ br, const float* __restrict__ bi,
                               float* __restrict__ bc) {
  const int i = blockIdx.x * 256 + threadIdx.x;
  if (i < D_DIM) bc[i] = br[i] + bi[i];
}

// ---------------- bf16 MFMA GEMM: C = A @ W^T (+bias) ----------------
// A: (M, K) bf16 row-major (optionally split at kSplit between A0/A1, each with row stride lda)
// W: (N, K) bf16 row-major (ldb = its K stride). 128x128 tile, BK=64, 4 waves (2x2 of 64x64).

#define BM 128
#define BN 128
#define BK 64

template <int EPI>  // 0: bf16 out, 1: bf16 out + f32 bias, 2: f32 out
__global__ __launch_bounds__(256) void gemm_bt_kernel(
    const u16* __restrict__ A0, const u16* __restrict__ A1, int kSplit, int lda,
    const u16* __restrict__ Bw, int ldb,
    const float* __restrict__ bias,
    void* __restrict__ C, int ldc, int K)
{
  __shared__ u16 As[BM * BK] __attribute__((aligned(16)));
  __shared__ u16 Bs[BN * BK] __attribute__((aligned(16)));
  const int tid = threadIdx.x;
  const int lane = tid & 63;
  const int w = tid >> 6;
  const int wr = w >> 1, wc = w & 1;
  const size_t rowBase = (size_t)blockIdx.y * BM;
  const size_t colBase = (size_t)blockIdx.x * BN;

  f32x4 zero = {0.f, 0.f, 0.f, 0.f};
  f32x4 acc[4][4];
#pragma unroll
  for (int i = 0; i < 4; ++i)
#pragma unroll
    for (int j = 0; j < 4; ++j) acc[i][j] = zero;

  const int ldRow = tid >> 3;        // 0..31 (row within a 32-row chunk)
  const int ldCol = (tid & 7) * 8;   // 8 bf16 = 16B per lane

  for (int kb = 0; kb < K; kb += BK) {
    const u16* Ab; int kc;
    if (kb < kSplit) { Ab = A0; kc = kb; } else { Ab = A1; kc = kb - kSplit; }
#pragma unroll
    for (int i = 0; i < 4; ++i) {
      const u16* g = Ab + (rowBase + i * 32 + ldRow) * (size_t)lda + kc + ldCol;
      gload16(g, &As[i * 2048 + tid * 8]);
    }
#pragma unroll
    for (int i = 0; i < 4; ++i) {
      const u16* g = Bw + (colBase + i * 32 + ldRow) * (size_t)ldb + kb + ldCol;
      gload16(g, &Bs[i * 2048 + tid * 8]);
    }
    __syncthreads();  // drains vmcnt(0): tiles resident
#pragma unroll
    for (int kk = 0; kk < 2; ++kk) {
      const int ko = kk * 32 + (lane >> 4) * 8;
      bf16x8 af[4], bfr[4];
#pragma unroll
      for (int mi = 0; mi < 4; ++mi)
        af[mi] = *(const bf16x8*)&As[(wr * 64 + mi * 16 + (lane & 15)) * BK + ko];
#pragma unroll
      for (int ni = 0; ni < 4; ++ni)
        bfr[ni] = *(const bf16x8*)&Bs[(wc * 64 + ni * 16 + (lane & 15)) * BK + ko];
#pragma unroll
      for (int mi = 0; mi < 4; ++mi)
#pragma unroll
        for (int ni = 0; ni < 4; ++ni)
          acc[mi][ni] = __builtin_amdgcn_mfma_f32_16x16x32_bf16(af[mi], bfr[ni], acc[mi][ni], 0, 0, 0);
    }
    __syncthreads();  // compute done -> LDS reusable
  }

#pragma unroll
  for (int mi = 0; mi < 4; ++mi)
#pragma unroll
    for (int ni = 0; ni < 4; ++ni) {
      const size_t col = colBase + wc * 64 + ni * 16 + (lane & 15);
      const float badd = (EPI == 1) ? bias[col] : 0.0f;
#pragma unroll
      for (int r = 0; r < 4; ++r) {
        const size_t row = rowBase + wr * 64 + mi * 16 + (lane >> 4) * 4 + r;
        const float v = acc[mi][ni][r] + badd;
        if (EPI == 2) ((float*)C)[row * (size_t)ldc + col] = v;
        else          ((u16*)C)[row * (size_t)ldc + col] = f2bf(v);
      }
    }
}

// ---------------- LayerNorm (in-place on bf16 rows) ----------------

__global__ __launch_bounds__(256) void ln_kernel(u16* __restrict__ xc,
    const float* __restrict__ gamma, const float* __restrict__ beta)
{
  const size_t row = blockIdx.x;
  u16* p = xc + row * D_DIM;
  const int tid = threadIdx.x;
  const int c = tid * 4;
  const uint2 raw = *(const uint2*)(p + c);
  const float v0 = bf2f((u16)(raw.x & 0xffff)), v1 = bf2f((u16)(raw.x >> 16));
  const float v2 = bf2f((u16)(raw.y & 0xffff)), v3 = bf2f((u16)(raw.y >> 16));
  float s = v0 + v1 + v2 + v3;
  float q = v0 * v0 + v1 * v1 + v2 * v2 + v3 * v3;
#pragma unroll
  for (int o = 32; o > 0; o >>= 1) { s += __shfl_xor(s, o); q += __shfl_xor(q, o); }
  __shared__ float red[8];
  if ((tid & 63) == 0) { red[(tid >> 6) * 2] = s; red[(tid >> 6) * 2 + 1] = q; }
  __syncthreads();
  s = red[0] + red[2] + red[4] + red[6];
  q = red[1] + red[3] + red[5] + red[7];
  const float mu = s * (1.0f / D_DIM);
  const float var = q * (1.0f / D_DIM) - mu * mu;
  const float rstd = 1.0f / sqrtf(var + 1e-5f);
  const float y0 = (v0 - mu) * rstd * gamma[c] + beta[c];
  const float y1 = (v1 - mu) * rstd * gamma[c + 1] + beta[c + 1];
  const float y2 = (v2 - mu) * rstd * gamma[c + 2] + beta[c + 2];
  const float y3 = (v3 - mu) * rstd * gamma[c + 3] + beta[c + 3];
  const uint32_t o0 = (uint32_t)f2bf(y0) | ((uint32_t)f2bf(y1) << 16);
  const uint32_t o1 = (uint32_t)f2bf(y2) | ((uint32_t)f2bf(y3) << 16);
  *(uint2*)(p + c) = make_uint2(o0, o1);
}

// ---------------- gate[row,h] = sigmoid(q.k / sqrt(DH)) — one wave per (row,h) ----------------

__global__ __launch_bounds__(256) void gate_kernel(
    const u16* __restrict__ Q, const u16* __restrict__ Kb, float* __restrict__ gate)
{
  const int gw = blockIdx.x * 4 + (threadIdx.x >> 6);   // wave id: row*8 + h
  const int lane = threadIdx.x & 63;
  const size_t row = (size_t)(gw >> 3);
  const int h = gw & 7;
  const size_t off = row * D_DIM + h * DH_DIM + lane * 2;
  const uint32_t qr = *(const uint32_t*)(Q + off);
  const uint32_t kr = *(const uint32_t*)(Kb + off);
  float d = bf2f((u16)(qr & 0xffff)) * bf2f((u16)(kr & 0xffff))
          + bf2f((u16)(qr >> 16))    * bf2f((u16)(kr >> 16));
#pragma unroll
  for (int o = 32; o > 0; o >>= 1) d += __shfl_xor(d, o);
  if (lane == 0) {
    const float x = d * 0.08838834764831845f;  // 1/sqrt(128)
    gate[gw] = 1.0f / (1.0f + expf(-x));
  }
}

// ---------------- sequential EMA scan over T (parallel over B*D) ----------------

__global__ __launch_bounds__(256) void scan_kernel(
    const u16* __restrict__ vb, const float* __restrict__ gate,
    const float* __restrict__ vstate, const float* __restrict__ log_alpha,
    u16* __restrict__ ret, float* __restrict__ fstate)
{
  const int gid = blockIdx.x * 256 + threadIdx.x;   // b*1024 + h*128 + d
  const int b = gid >> 10;
  const int c = gid & 1023;
  const int h = c >> 7;
  const float alpha = 1.0f / (1.0f + expf(-log_alpha[h]));
  const float oma = 1.0f - alpha;
  float state = vstate[gid];
  const u16* vp = vb + (size_t)b * D_DIM + c;
  u16* rp = ret + (size_t)b * D_DIM + c;
  const float* gp = gate + b * H_DIM + h;
#pragma unroll 4
  for (int t = 0; t < T_DIM; ++t) {
    const float v = bf2f(vp[(size_t)t * (B_DIM * D_DIM)]);
    const float g = gp[(size_t)t * (B_DIM * H_DIM)];
    state = alpha * v + oma * state;
    rp[(size_t)t * (B_DIM * D_DIM)] = f2bf(g * state);
  }
  fstate[gid] = state;
}

// ---------------- launch ----------------

extern "C" void kernel_launch(void* const* d_in, const int* in_sizes, int n_in,
                              void* d_out, int out_size, void* d_ws, size_t ws_size,
                              hipStream_t stream) {
  const float* x_real      = (const float*)d_in[0];
  const float* x_imag      = (const float*)d_in[1];
  const float* value_state = (const float*)d_in[2];
  // d_in[3] = t (unused by the math)
  const float* Wr_in  = (const float*)d_in[4];
  const float* Wi_in  = (const float*)d_in[5];
  const float* br_in  = (const float*)d_in[6];
  const float* bi_in  = (const float*)d_in[7];
  const float* ln_g   = (const float*)d_in[8];
  const float* ln_b   = (const float*)d_in[9];
  const float* W_qkv  = (const float*)d_in[10];
  const float* log_alpha = (const float*)d_in[11];
  const float* Wr_out = (const float*)d_in[12];
  const float* Wi_out = (const float*)d_in[13];

  float* out_real = (float*)d_out;
  float* out_imag = out_real + (size_t)MROWS * D_DIM;
  float* fstate   = out_imag + (size_t)MROWS * D_DIM;

  // Scratch carved out of d_out's out_real region (dead until the final GEMMs):
  //   R0a: [0, 67MB)   xr_bf16 -> Q -> v        (dead before out_real GEMM writes)
  //   xc : [67, 134MB) input-proj out, LN in place (dead before out_real GEMM writes)
  u16* R0a = (u16*)d_out;
  u16* xc  = (u16*)((char*)d_out + (size_t)MROWS * D_DIM * 2);

  // d_ws buffers (~83 MB total)
  char* ws = (char*)d_ws;
  size_t off = 0;
  auto alloc = [&](size_t bytes) { void* p = ws + off; off += (bytes + 255) & ~(size_t)255; return p; };
  u16*   Wc    = (u16*)alloc((size_t)1024 * 2048 * 2);
  u16*   Wqkvb = (u16*)alloc((size_t)3072 * 1024 * 2);
  u16*   Wrob  = (u16*)alloc((size_t)1024 * 1024 * 2);
  u16*   Wiob  = (u16*)alloc((size_t)1024 * 1024 * 2);
  float* bc    = (float*)alloc((size_t)D_DIM * 4);
  u16*   R0b   = (u16*)alloc((size_t)MROWS * D_DIM * 2);  // xi_bf16 -> K -> retrieved
  float* gate  = (float*)alloc((size_t)MROWS * H_DIM * 4);

  // --- weight prep ---
  prep_wc_kernel<<<(1024 * 2048) / 256, 256, 0, stream>>>(Wr_in, Wi_in, Wc);
  prep_bc_kernel<<<4, 256, 0, stream>>>(br_in, bi_in, bc);
  cast_bf16_kernel<<<1536, 256, 0, stream>>>(W_qkv, Wqkvb, (size_t)3072 * 1024 / 8);
  cast_bf16_kernel<<<512, 256, 0, stream>>>(Wr_out, Wrob, (size_t)1024 * 1024 / 8);
  cast_bf16_kernel<<<512, 256, 0, stream>>>(Wi_out, Wiob, (size_t)1024 * 1024 / 8);
  // --- activation casts ---
  cast_bf16_kernel<<<4096, 256, 0, stream>>>(x_real, R0a, (size_t)MROWS * D_DIM / 8);
  cast_bf16_kernel<<<4096, 256, 0, stream>>>(x_imag, R0b, (size_t)MROWS * D_DIM / 8);

  const dim3 g8(D_DIM / BN, MROWS / BM);  // (8, 256)
  // input proj: xc_pre = [xr|xi] @ [Wc]^T + bc   (K=2048, split at 1024)
  gemm_bt_kernel<1><<<g8, 256, 0, stream>>>(R0a, R0b, 1024, 1024, Wc, 2048, bc, xc, 1024, 2048);
  // LayerNorm in place
  ln_kernel<<<MROWS, 256, 0, stream>>>(xc, ln_g, ln_b);
  // Q -> R0a, K -> R0b
  gemm_bt_kernel<0><<<g8, 256, 0, stream>>>(xc, xc, 1024, 1024, Wqkvb, 1024, nullptr, R0a, 1024, 1024);
  gemm_bt_kernel<0><<<g8, 256, 0, stream>>>(xc, xc, 1024, 1024, Wqkvb + (size_t)1024 * 1024, 1024, nullptr, R0b, 1024, 1024);
  // gate
  gate_kernel<<<(MROWS * H_DIM) / 4, 256, 0, stream>>>(R0a, R0b, gate);
  // V -> R0a (overwrites dead Q)
  gemm_bt_kernel<0><<<g8, 256, 0, stream>>>(xc, xc, 1024, 1024, Wqkvb + (size_t)2 * 1024 * 1024, 1024, nullptr, R0a, 1024, 1024);
  // EMA scan: retrieved -> R0b (overwrites dead K), final_state -> d_out tail
  scan_kernel<<<(B_DIM * D_DIM) / 256, 256, 0, stream>>>(R0a, gate, value_state, log_alpha, R0b, fstate);
  // output projections (f32), overwrite the d_out scratch regions
  gemm_bt_kernel<2><<<g8, 256, 0, stream>>>(R0b, R0b, 1024, 1024, Wrob, 1024, nullptr, out_real, 1024, 1024);
  gemm_bt_kernel<2><<<g8, 256, 0, stream>>>(R0b, R0b, 1024, 1024, Wiob, 1024, nullptr, out_imag, 1024, 1024);
}

// Round 2
// 985.729 us; speedup vs baseline: 1.0485x; 1.0485x over previous
//
#include <hip/hip_runtime.h>
#include <stdint.h>

#define T_DIM 512
#define B_DIM 64
#define D_DIM 1024
#define H_DIM 8
#define DH_DIM 128
#define MROWS (T_DIM * B_DIM)   // 32768 rows across all timesteps

typedef unsigned short u16;
typedef __attribute__((ext_vector_type(8))) __bf16 bf16x8;
typedef __attribute__((ext_vector_type(4))) float f32x4;

__device__ __forceinline__ u16 f2bf(float f) {
  union { float f; uint32_t u; } v; v.f = f;
  uint32_t u = v.u;
  u += 0x7fffu + ((u >> 16) & 1u);   // RNE
  return (u16)(u >> 16);
}
__device__ __forceinline__ float bf2f(u16 h) {
  union { uint32_t u; float f; } v; v.u = ((uint32_t)h) << 16;
  return v.f;
}

__device__ __forceinline__ void gload16(const void* g, void* l) {
  __builtin_amdgcn_global_load_lds(
      (const __attribute__((address_space(1))) uint32_t*)g,
      (__attribute__((address_space(3))) uint32_t*)l, 16, 0, 0);
}

// ---------------- elementwise prep ----------------

__global__ void cast_bf16_kernel(const float* __restrict__ in, u16* __restrict__ out, size_t n8) {
  size_t i = (size_t)blockIdx.x * blockDim.x + threadIdx.x;
  const size_t stride = (size_t)gridDim.x * blockDim.x;
  for (; i < n8; i += stride) {
    const float4 a = ((const float4*)in)[i * 2];
    const float4 b = ((const float4*)in)[i * 2 + 1];
    union { u16 h[8]; uint4 u; } o;
    o.h[0] = f2bf(a.x); o.h[1] = f2bf(a.y); o.h[2] = f2bf(a.z); o.h[3] = f2bf(a.w);
    o.h[4] = f2bf(b.x); o.h[5] = f2bf(b.y); o.h[6] = f2bf(b.z); o.h[7] = f2bf(b.w);
    ((uint4*)out)[i] = o.u;
  }
}

// Wc[n][k] = Wr[n][k]+Wi[n][k] (k<1024)  |  Wr[n][k-1024]-Wi[n][k-1024]  -> (1024, 2048) bf16
__global__ void prep_wc_kernel(const float* __restrict__ Wr, const float* __restrict__ Wi,
                               u16* __restrict__ Wc) {
  const int idx = blockIdx.x * 256 + threadIdx.x;  // over 1024*2048
  const int n = idx >> 11;
  const int k = idx & 2047;
  const int kk = k & 1023;
  const float a = Wr[n * 1024 + kk], b = Wi[n * 1024 + kk];
  Wc[idx] = f2bf(k < 1024 ? a + b : a - b);
}

__global__ void prep_bc_kernel(const float* __restrict__ br, const float* __restrict__ bi,
                               float* __restrict__ bc) {
  const int i = blockIdx.x * 256 + threadIdx.x;
  if (i < D_DIM) bc[i] = br[i] + bi[i];
}

// ---------------- bf16 MFMA GEMM: C = A @ W^T (+bias) ----------------
// A: (M, K) bf16 row-major (optionally split at kSplit between A0/A1, each row stride lda)
// W: (N, K) bf16 row-major. 128x128 tile, BK=64, 4 waves (2x2 of 64x64).
// 1-D grid with XCD-contiguous swizzle: bid%8 -> XCD; each XCD owns a contiguous
// band of (MROWS/BM)/8 = 32 row panels enumerated ROW-MAJOR (the nColBlk blocks
// sharing an A panel are adjacent in the XCD's issue order -> A panel stays in L2).
// EPI: 1 = bf16 out + f32 bias (single C0)
//      3 = bf16 out, 3-way 1024-col segment select (Q|K|V)
//      2 = f32 out, 2-way 1024-col segment select (out_real|out_imag)

#define BM 128
#define BN 128
#define BK 64

template <int EPI>
__global__ __launch_bounds__(256) void gemm_bt_kernel(
    const u16* __restrict__ A0, const u16* __restrict__ A1, int kSplit, int lda,
    const u16* __restrict__ Bw, int ldb,
    const float* __restrict__ bias,
    void* __restrict__ C0, void* __restrict__ C1, void* __restrict__ C2,
    int ldc, int K, int nColBlk)
{
  __shared__ u16 As[BM * BK] __attribute__((aligned(16)));
  __shared__ u16 Bs[BN * BK] __attribute__((aligned(16)));
  const int tid = threadIdx.x;
  const int lane = tid & 63;
  const int w = tid >> 6;
  const int wr = w >> 1, wc = w & 1;

  // XCD-contiguous swizzle
  const int bid = blockIdx.x;
  const int xcd = bid & 7;
  const int local = bid >> 3;
  const int rowL = local / nColBlk;
  const int colB = local - rowL * nColBlk;
  const int rowB = xcd * ((MROWS / BM) / 8) + rowL;
  const size_t rowBase = (size_t)rowB * BM;
  const size_t colBase = (size_t)colB * BN;

  f32x4 zero = {0.f, 0.f, 0.f, 0.f};
  f32x4 acc[4][4];
#pragma unroll
  for (int i = 0; i < 4; ++i)
#pragma unroll
    for (int j = 0; j < 4; ++j) acc[i][j] = zero;

  const int ldRow = tid >> 3;        // 0..31 (row within a 32-row chunk)
  const int ldCol = (tid & 7) * 8;   // 8 bf16 = 16B per lane

  for (int kb = 0; kb < K; kb += BK) {
    const u16* Ab; int kc;
    if (kb < kSplit) { Ab = A0; kc = kb; } else { Ab = A1; kc = kb - kSplit; }
#pragma unroll
    for (int i = 0; i < 4; ++i) {
      const u16* g = Ab + (rowBase + i * 32 + ldRow) * (size_t)lda + kc + ldCol;
      gload16(g, &As[i * 2048 + tid * 8]);
    }
#pragma unroll
    for (int i = 0; i < 4; ++i) {
      const u16* g = Bw + (colBase + i * 32 + ldRow) * (size_t)ldb + kb + ldCol;
      gload16(g, &Bs[i * 2048 + tid * 8]);
    }
    __syncthreads();  // drains vmcnt(0): tiles resident
#pragma unroll
    for (int kk = 0; kk < 2; ++kk) {
      const int ko = kk * 32 + (lane >> 4) * 8;
      bf16x8 af[4], bfr[4];
#pragma unroll
      for (int mi = 0; mi < 4; ++mi)
        af[mi] = *(const bf16x8*)&As[(wr * 64 + mi * 16 + (lane & 15)) * BK + ko];
#pragma unroll
      for (int ni = 0; ni < 4; ++ni)
        bfr[ni] = *(const bf16x8*)&Bs[(wc * 64 + ni * 16 + (lane & 15)) * BK + ko];
#pragma unroll
      for (int mi = 0; mi < 4; ++mi)
#pragma unroll
        for (int ni = 0; ni < 4; ++ni)
          acc[mi][ni] = __builtin_amdgcn_mfma_f32_16x16x32_bf16(af[mi], bfr[ni], acc[mi][ni], 0, 0, 0);
    }
    __syncthreads();  // compute done -> LDS reusable
  }

  // epilogue: segment-select output buffer (BN=128 divides 1024, so the whole
  // block lies in one 1024-col segment -> selection is block-uniform)
  const int seg = (int)(colBase >> 10);
  const size_t colSeg = colBase & 1023;
  void* Cout;
  if (EPI == 3)      Cout = (seg == 0) ? C0 : (seg == 1) ? C1 : C2;
  else if (EPI == 2) Cout = (seg == 0) ? C0 : C1;
  else               Cout = C0;

#pragma unroll
  for (int mi = 0; mi < 4; ++mi)
#pragma unroll
    for (int ni = 0; ni < 4; ++ni) {
      const int cn = wc * 64 + ni * 16 + (lane & 15);
      const float badd = (EPI == 1) ? bias[colBase + cn] : 0.0f;
      const size_t col = colSeg + cn;
#pragma unroll
      for (int r = 0; r < 4; ++r) {
        const size_t row = rowBase + wr * 64 + mi * 16 + (lane >> 4) * 4 + r;
        const float v = acc[mi][ni][r] + badd;
        if (EPI == 2) ((float*)Cout)[row * (size_t)ldc + col] = v;
        else          ((u16*)Cout)[row * (size_t)ldc + col] = f2bf(v);
      }
    }
}

// ---------------- LayerNorm (in-place on bf16 rows) ----------------

__global__ __launch_bounds__(256) void ln_kernel(u16* __restrict__ xc,
    const float* __restrict__ gamma, const float* __restrict__ beta)
{
  const size_t row = blockIdx.x;
  u16* p = xc + row * D_DIM;
  const int tid = threadIdx.x;
  const int c = tid * 4;
  const uint2 raw = *(const uint2*)(p + c);
  const float v0 = bf2f((u16)(raw.x & 0xffff)), v1 = bf2f((u16)(raw.x >> 16));
  const float v2 = bf2f((u16)(raw.y & 0xffff)), v3 = bf2f((u16)(raw.y >> 16));
  float s = v0 + v1 + v2 + v3;
  float q = v0 * v0 + v1 * v1 + v2 * v2 + v3 * v3;
#pragma unroll
  for (int o = 32; o > 0; o >>= 1) { s += __shfl_xor(s, o); q += __shfl_xor(q, o); }
  __shared__ float red[8];
  if ((tid & 63) == 0) { red[(tid >> 6) * 2] = s; red[(tid >> 6) * 2 + 1] = q; }
  __syncthreads();
  s = red[0] + red[2] + red[4] + red[6];
  q = red[1] + red[3] + red[5] + red[7];
  const float mu = s * (1.0f / D_DIM);
  const float var = q * (1.0f / D_DIM) - mu * mu;
  const float rstd = 1.0f / sqrtf(var + 1e-5f);
  const float y0 = (v0 - mu) * rstd * gamma[c] + beta[c];
  const float y1 = (v1 - mu) * rstd * gamma[c + 1] + beta[c + 1];
  const float y2 = (v2 - mu) * rstd * gamma[c + 2] + beta[c + 2];
  const float y3 = (v3 - mu) * rstd * gamma[c + 3] + beta[c + 3];
  const uint32_t o0 = (uint32_t)f2bf(y0) | ((uint32_t)f2bf(y1) << 16);
  const uint32_t o1 = (uint32_t)f2bf(y2) | ((uint32_t)f2bf(y3) << 16);
  *(uint2*)(p + c) = make_uint2(o0, o1);
}

// ---------------- gate[row,h] = sigmoid(q.k / sqrt(DH)) — one wave per (row,h) ----------------

__global__ __launch_bounds__(256) void gate_kernel(
    const u16* __restrict__ Q, const u16* __restrict__ Kb, float* __restrict__ gate)
{
  const int gw = blockIdx.x * 4 + (threadIdx.x >> 6);   // wave id: row*8 + h
  const int lane = threadIdx.x & 63;
  const size_t row = (size_t)(gw >> 3);
  const int h = gw & 7;
  const size_t off = row * D_DIM + h * DH_DIM + lane * 2;
  const uint32_t qr = *(const uint32_t*)(Q + off);
  const uint32_t kr = *(const uint32_t*)(Kb + off);
  float d = bf2f((u16)(qr & 0xffff)) * bf2f((u16)(kr & 0xffff))
          + bf2f((u16)(qr >> 16))    * bf2f((u16)(kr >> 16));
#pragma unroll
  for (int o = 32; o > 0; o >>= 1) d += __shfl_xor(d, o);
  if (lane == 0) {
    const float x = d * 0.08838834764831845f;  // 1/sqrt(128)
    gate[gw] = 1.0f / (1.0f + expf(-x));
  }
}

// ---------------- sequential EMA scan over T (parallel over B*D) ----------------

__global__ __launch_bounds__(256) void scan_kernel(
    const u16* __restrict__ vb, const float* __restrict__ gate,
    const float* __restrict__ vstate, const float* __restrict__ log_alpha,
    u16* __restrict__ ret, float* __restrict__ fstate)
{
  const int gid = blockIdx.x * 256 + threadIdx.x;   // b*1024 + h*128 + d
  const int b = gid >> 10;
  const int c = gid & 1023;
  const int h = c >> 7;
  const float alpha = 1.0f / (1.0f + expf(-log_alpha[h]));
  const float oma = 1.0f - alpha;
  float state = vstate[gid];
  const u16* vp = vb + (size_t)b * D_DIM + c;
  u16* rp = ret + (size_t)b * D_DIM + c;
  const float* gp = gate + b * H_DIM + h;
#pragma unroll 4
  for (int t = 0; t < T_DIM; ++t) {
    const float v = bf2f(vp[(size_t)t * (B_DIM * D_DIM)]);
    const float g = gp[(size_t)t * (B_DIM * H_DIM)];
    state = alpha * v + oma * state;
    rp[(size_t)t * (B_DIM * D_DIM)] = f2bf(g * state);
  }
  fstate[gid] = state;
}

// ---------------- launch ----------------

extern "C" void kernel_launch(void* const* d_in, const int* in_sizes, int n_in,
                              void* d_out, int out_size, void* d_ws, size_t ws_size,
                              hipStream_t stream) {
  const float* x_real      = (const float*)d_in[0];
  const float* x_imag      = (const float*)d_in[1];
  const float* value_state = (const float*)d_in[2];
  // d_in[3] = t (unused by the math)
  const float* Wr_in  = (const float*)d_in[4];
  const float* Wi_in  = (const float*)d_in[5];
  const float* br_in  = (const float*)d_in[6];
  const float* bi_in  = (const float*)d_in[7];
  const float* ln_g   = (const float*)d_in[8];
  const float* ln_b   = (const float*)d_in[9];
  const float* W_qkv  = (const float*)d_in[10];
  const float* log_alpha = (const float*)d_in[11];
  const float* Wr_out = (const float*)d_in[12];
  const float* Wi_out = (const float*)d_in[13];

  float* out_real = (float*)d_out;
  float* out_imag = out_real + (size_t)MROWS * D_DIM;
  float* fstate   = out_imag + (size_t)MROWS * D_DIM;

  // Scratch carved out of d_out (regions dead until the final out-proj GEMM):
  //   R0a: [0, 67MB)        xr_bf16 -> Q            (out_real region)
  //   xc : [67, 134MB)      input-proj out, LN'd    (out_real region)
  //   Vb : out_imag region  V                        (dead after scan)
  u16* R0a = (u16*)d_out;
  u16* xc  = (u16*)((char*)d_out + (size_t)MROWS * D_DIM * 2);
  u16* Vb  = (u16*)out_imag;

  // d_ws buffers (~82 MB total)
  char* ws = (char*)d_ws;
  size_t off = 0;
  auto alloc = [&](size_t bytes) { void* p = ws + off; off += (bytes + 255) & ~(size_t)255; return p; };
  u16*   Wc    = (u16*)alloc((size_t)1024 * 2048 * 2);
  u16*   Wqkvb = (u16*)alloc((size_t)3072 * 1024 * 2);
  u16*   Wob   = (u16*)alloc((size_t)2048 * 1024 * 2);   // [Wr_out; Wi_out]
  float* bc    = (float*)alloc((size_t)D_DIM * 4);
  u16*   R0b   = (u16*)alloc((size_t)MROWS * D_DIM * 2); // xi_bf16 -> K -> retrieved
  float* gate  = (float*)alloc((size_t)MROWS * H_DIM * 4);

  // --- weight prep ---
  prep_wc_kernel<<<(1024 * 2048) / 256, 256, 0, stream>>>(Wr_in, Wi_in, Wc);
  prep_bc_kernel<<<4, 256, 0, stream>>>(br_in, bi_in, bc);
  cast_bf16_kernel<<<1536, 256, 0, stream>>>(W_qkv, Wqkvb, (size_t)3072 * 1024 / 8);
  cast_bf16_kernel<<<512, 256, 0, stream>>>(Wr_out, Wob, (size_t)1024 * 1024 / 8);
  cast_bf16_kernel<<<512, 256, 0, stream>>>(Wi_out, Wob + (size_t)1024 * 1024, (size_t)1024 * 1024 / 8);
  // --- activation casts ---
  cast_bf16_kernel<<<4096, 256, 0, stream>>>(x_real, R0a, (size_t)MROWS * D_DIM / 8);
  cast_bf16_kernel<<<4096, 256, 0, stream>>>(x_imag, R0b, (size_t)MROWS * D_DIM / 8);

  // input proj: xc_pre = [xr|xi] @ Wc^T + bc   (K=2048, split at 1024) -> xc
  gemm_bt_kernel<1><<<dim3(256 * 8), 256, 0, stream>>>(
      R0a, R0b, 1024, 1024, Wc, 2048, bc, xc, nullptr, nullptr, 1024, 2048, 8);
  // LayerNorm in place
  ln_kernel<<<MROWS, 256, 0, stream>>>(xc, ln_g, ln_b);
  // QKV in ONE GEMM (N=3072): Q -> R0a, K -> R0b, V -> Vb
  gemm_bt_kernel<3><<<dim3(256 * 24), 256, 0, stream>>>(
      xc, xc, 1024, 1024, Wqkvb, 1024, nullptr, R0a, R0b, Vb, 1024, 1024, 24);
  // gate from Q,K
  gate_kernel<<<(MROWS * H_DIM) / 4, 256, 0, stream>>>(R0a, R0b, gate);
  // EMA scan: retrieved -> R0b (overwrites dead K), final_state -> d_out tail
  scan_kernel<<<(B_DIM * D_DIM) / 256, 256, 0, stream>>>(Vb, gate, value_state, log_alpha, R0b, fstate);
  // output projections in ONE GEMM (N=2048, f32 out): -> out_real | out_imag
  gemm_bt_kernel<2><<<dim3(256 * 16), 256, 0, stream>>>(
      R0b, R0b, 1024, 1024, Wob, 1024, nullptr, out_real, out_imag, nullptr, 1024, 1024, 16);
}

// Round 3
// 797.160 us; speedup vs baseline: 1.2965x; 1.2366x over previous
//
#include <hip/hip_runtime.h>
#include <stdint.h>

#define T_DIM 512
#define B_DIM 64
#define D_DIM 1024
#define H_DIM 8
#define DH_DIM 128
#define MROWS (T_DIM * B_DIM)   // 32768 rows across all timesteps

typedef unsigned short u16;
typedef __attribute__((ext_vector_type(8))) __bf16 bf16x8;
typedef __attribute__((ext_vector_type(4))) float f32x4;

__device__ __forceinline__ u16 f2bf(float f) {
  union { float f; uint32_t u; } v; v.f = f;
  uint32_t u = v.u;
  u += 0x7fffu + ((u >> 16) & 1u);   // RNE
  return (u16)(u >> 16);
}
__device__ __forceinline__ float bf2f(u16 h) {
  union { uint32_t u; float f; } v; v.u = ((uint32_t)h) << 16;
  return v.f;
}

__device__ __forceinline__ void gload16(const void* g, void* l) {
  __builtin_amdgcn_global_load_lds(
      (const __attribute__((address_space(1))) uint32_t*)g,
      (__attribute__((address_space(3))) uint32_t*)l, 16, 0, 0);
}

// ---------------- elementwise prep ----------------

__global__ void cast_bf16_kernel(const float* __restrict__ in, u16* __restrict__ out, size_t n8) {
  size_t i = (size_t)blockIdx.x * blockDim.x + threadIdx.x;
  const size_t stride = (size_t)gridDim.x * blockDim.x;
  for (; i < n8; i += stride) {
    const float4 a = ((const float4*)in)[i * 2];
    const float4 b = ((const float4*)in)[i * 2 + 1];
    union { u16 h[8]; uint4 u; } o;
    o.h[0] = f2bf(a.x); o.h[1] = f2bf(a.y); o.h[2] = f2bf(a.z); o.h[3] = f2bf(a.w);
    o.h[4] = f2bf(b.x); o.h[5] = f2bf(b.y); o.h[6] = f2bf(b.z); o.h[7] = f2bf(b.w);
    ((uint4*)out)[i] = o.u;
  }
}

// Wc[n][k] = Wr[n][k]+Wi[n][k] (k<1024)  |  Wr[n][k-1024]-Wi[n][k-1024]  -> (1024, 2048) bf16
__global__ void prep_wc_kernel(const float* __restrict__ Wr, const float* __restrict__ Wi,
                               u16* __restrict__ Wc) {
  const int idx = blockIdx.x * 256 + threadIdx.x;  // over 1024*2048
  const int n = idx >> 11;
  const int k = idx & 2047;
  const int kk = k & 1023;
  const float a = Wr[n * 1024 + kk], b = Wi[n * 1024 + kk];
  Wc[idx] = f2bf(k < 1024 ? a + b : a - b);
}

__global__ void prep_bc_kernel(const float* __restrict__ br, const float* __restrict__ bi,
                               float* __restrict__ bc) {
  const int i = blockIdx.x * 256 + threadIdx.x;
  if (i < D_DIM) bc[i] = br[i] + bi[i];
}

// ---------------- 256x256 pipelined bf16 MFMA GEMM: C = A @ W^T (+bias) ----------------
// 512 threads = 8 waves (2 M x 4 N), per-wave output 128x64, BK=64.
// LDS (dynamic 128 KB): [buf:2][ A: [kh:2][256 r][4 u][8] | B: same ]  (slot = 16 KB)
// Schedule per K-tile t (cur = t&1):
//   vmcnt(4); barrier;                      // tile t fully resident (newest 4-load group may fly)
//   stage (t+1).k1 -> buf[cur^1].k1         // slot last read in tile t-1 (safe after barrier)
//   phases 0-3: quadrants of ksub 0
//   barrier;
//   stage (t+2).k0 -> buf[cur].k0           // slot just freed by phases 0-3
//   phases 4-7: quadrants of ksub 1
// Prologue stages t0.k0, t0.k1, t1.k0 (12 loads). vmcnt never drained to 0 in the loop (T4).
// LDS 16B-unit XOR swizzle u ^= (r&3)^((r>>2)&3), pre-swizzled on the GLOBAL source (rule #21);
// read-side unit offset collapses to a lane-only constant. setprio around MFMA clusters (T5).
// EPI: 1 = bf16 out + f32 bias; 3 = bf16 out, 3-way 1024-col segment; 2 = f32 out, 2-way segment.

template <int EPI>
__global__ __launch_bounds__(512, 2) void gemm256_kernel(
    const u16* __restrict__ A0, const u16* __restrict__ A1, int kSplit, int lda,
    const u16* __restrict__ Bw, int ldb,
    const float* __restrict__ bias,
    void* __restrict__ C0, void* __restrict__ C1, void* __restrict__ C2,
    int ldc, int K, int nColBlk)
{
  extern __shared__ u16 lds[];   // 65536 u16 = 128 KB
  const int tid  = threadIdx.x;
  const int lane = tid & 63;
  const int w    = tid >> 6;
  const int wr   = w >> 2;       // 0..1
  const int wc   = w & 3;        // 0..3

  // XCD-contiguous swizzle: bid%8 -> XCD, 16 row-panels per XCD, row-major within band
  const int bid   = blockIdx.x;
  const int xcd   = bid & 7;
  const int local = bid >> 3;
  const int rowL  = local / nColBlk;
  const int colB  = local - rowL * nColBlk;
  const size_t rowBase = (size_t)(xcd * 16 + rowL) * 256;
  const size_t colBase = (size_t)colB * 256;

  f32x4 acc[8][4];
#pragma unroll
  for (int i = 0; i < 8; ++i)
#pragma unroll
    for (int j = 0; j < 4; ++j) acc[i][j] = (f32x4){0.f, 0.f, 0.f, 0.f};

  const int NT = K >> 6;

  // stage one k-half (A+B) of tile t into buf: 4 gload16 per thread
  auto stage = [&](int buf, int kh, int t) {
    const int kb = t * 64;
    const u16* Ab; int kc;
    if (kb < kSplit) { Ab = A0; kc = kb; } else { Ab = A1; kc = kb - kSplit; }
    u16* sA = lds + buf * 32768 + kh * 8192;
    u16* sB = lds + buf * 32768 + 16384 + kh * 8192;
#pragma unroll
    for (int i = 0; i < 2; ++i) {
      const int l = i * 512 + tid;
      const int r = l >> 2;
      const int ug = (l & 3) ^ (r & 3) ^ ((r >> 2) & 3);   // inverse-swizzled global k-unit
      gload16(Ab + (rowBase + r) * (size_t)lda + (kc + kh * 32 + ug * 8), sA + l * 8);
      gload16(Bw + (colBase + r) * (size_t)ldb + (kb + kh * 32 + ug * 8), sB + l * 8);
    }
  };

  const int uo = (((lane >> 4) ^ (lane & 3) ^ ((lane >> 2) & 3)) << 3);  // u16 units
  const int la = lane & 15;

  // compute one k-half: 4 quadrants x (6 ds_read_b128 + 8 MFMA)
  auto computeH = [&](int buf, int ks) {
    const u16* sA = lds + buf * 32768 + ks * 8192;
    const u16* sB = lds + buf * 32768 + 16384 + ks * 8192;
#pragma unroll
    for (int q = 0; q < 4; ++q) {
      const int qm = q >> 1, qn = q & 1;
      const int ra = wr * 128 + qm * 64 + la;
      const int rb = wc * 64 + qn * 32 + la;
      bf16x8 a[4], b[2];
#pragma unroll
      for (int j = 0; j < 4; ++j) a[j] = *(const bf16x8*)(sA + (ra + j * 16) * 32 + uo);
#pragma unroll
      for (int j = 0; j < 2; ++j) b[j] = *(const bf16x8*)(sB + (rb + j * 16) * 32 + uo);
      __builtin_amdgcn_s_setprio(1);
#pragma unroll
      for (int j = 0; j < 4; ++j)
#pragma unroll
        for (int j2 = 0; j2 < 2; ++j2)
          acc[qm * 4 + j][qn * 2 + j2] =
              __builtin_amdgcn_mfma_f32_16x16x32_bf16(a[j], b[j2], acc[qm * 4 + j][qn * 2 + j2], 0, 0, 0);
      __builtin_amdgcn_s_setprio(0);
    }
  };

  // prologue: tile0 (both halves) + tile1 k0  -> 12 loads in flight
  stage(0, 0, 0);
  stage(0, 1, 0);
  stage(1, 0, 1);

  int cur = 0;
  for (int t = 0; t < NT; ++t, cur ^= 1) {
    asm volatile("s_waitcnt vmcnt(4)" ::: "memory");
    __builtin_amdgcn_sched_barrier(0);
    __builtin_amdgcn_s_barrier();
    __builtin_amdgcn_sched_barrier(0);
    if (t + 1 < NT) stage(cur ^ 1, 1, t + 1);
    computeH(cur, 0);
    __builtin_amdgcn_sched_barrier(0);
    __builtin_amdgcn_s_barrier();
    __builtin_amdgcn_sched_barrier(0);
    if (t + 2 < NT) stage(cur, 0, t + 2);
    computeH(cur, 1);
    __builtin_amdgcn_sched_barrier(0);
  }

  // epilogue: segment-select output buffer (colBase multiple of 256 -> block-uniform segment)
  const int seg = (int)(colBase >> 10);
  const size_t colSeg = colBase & 1023;
  void* Cout;
  if (EPI == 3)      Cout = (seg == 0) ? C0 : (seg == 1) ? C1 : C2;
  else if (EPI == 2) Cout = (seg == 0) ? C0 : C1;
  else               Cout = C0;

#pragma unroll
  for (int mi = 0; mi < 8; ++mi)
#pragma unroll
    for (int ni = 0; ni < 4; ++ni) {
      const int cn = wc * 64 + ni * 16 + la;
      const float badd = (EPI == 1) ? bias[colBase + cn] : 0.0f;
      const size_t col = colSeg + cn;
#pragma unroll
      for (int r = 0; r < 4; ++r) {
        const size_t row = rowBase + wr * 128 + mi * 16 + (lane >> 4) * 4 + r;
        const float v = acc[mi][ni][r] + badd;
        if (EPI == 2) ((float*)Cout)[row * (size_t)ldc + col] = v;
        else          ((u16*)Cout)[row * (size_t)ldc + col] = f2bf(v);
      }
    }
}

// ---------------- LayerNorm (in-place on bf16 rows) ----------------

__global__ __launch_bounds__(256) void ln_kernel(u16* __restrict__ xc,
    const float* __restrict__ gamma, const float* __restrict__ beta)
{
  const size_t row = blockIdx.x;
  u16* p = xc + row * D_DIM;
  const int tid = threadIdx.x;
  const int c = tid * 4;
  const uint2 raw = *(const uint2*)(p + c);
  const float v0 = bf2f((u16)(raw.x & 0xffff)), v1 = bf2f((u16)(raw.x >> 16));
  const float v2 = bf2f((u16)(raw.y & 0xffff)), v3 = bf2f((u16)(raw.y >> 16));
  float s = v0 + v1 + v2 + v3;
  float q = v0 * v0 + v1 * v1 + v2 * v2 + v3 * v3;
#pragma unroll
  for (int o = 32; o > 0; o >>= 1) { s += __shfl_xor(s, o); q += __shfl_xor(q, o); }
  __shared__ float red[8];
  if ((tid & 63) == 0) { red[(tid >> 6) * 2] = s; red[(tid >> 6) * 2 + 1] = q; }
  __syncthreads();
  s = red[0] + red[2] + red[4] + red[6];
  q = red[1] + red[3] + red[5] + red[7];
  const float mu = s * (1.0f / D_DIM);
  const float var = q * (1.0f / D_DIM) - mu * mu;
  const float rstd = 1.0f / sqrtf(var + 1e-5f);
  const float y0 = (v0 - mu) * rstd * gamma[c] + beta[c];
  const float y1 = (v1 - mu) * rstd * gamma[c + 1] + beta[c + 1];
  const float y2 = (v2 - mu) * rstd * gamma[c + 2] + beta[c + 2];
  const float y3 = (v3 - mu) * rstd * gamma[c + 3] + beta[c + 3];
  const uint32_t o0 = (uint32_t)f2bf(y0) | ((uint32_t)f2bf(y1) << 16);
  const uint32_t o1 = (uint32_t)f2bf(y2) | ((uint32_t)f2bf(y3) << 16);
  *(uint2*)(p + c) = make_uint2(o0, o1);
}

// ---------------- gate[row,h] = sigmoid(q.k / sqrt(DH)) — one wave per (row,h) ----------------

__global__ __launch_bounds__(256) void gate_kernel(
    const u16* __restrict__ Q, const u16* __restrict__ Kb, float* __restrict__ gate)
{
  const int gw = blockIdx.x * 4 + (threadIdx.x >> 6);   // wave id: row*8 + h
  const int lane = threadIdx.x & 63;
  const size_t row = (size_t)(gw >> 3);
  const int h = gw & 7;
  const size_t off = row * D_DIM + h * DH_DIM + lane * 2;
  const uint32_t qr = *(const uint32_t*)(Q + off);
  const uint32_t kr = *(const uint32_t*)(Kb + off);
  float d = bf2f((u16)(qr & 0xffff)) * bf2f((u16)(kr & 0xffff))
          + bf2f((u16)(qr >> 16))    * bf2f((u16)(kr >> 16));
#pragma unroll
  for (int o = 32; o > 0; o >>= 1) d += __shfl_xor(d, o);
  if (lane == 0) {
    const float x = d * 0.08838834764831845f;  // 1/sqrt(128)
    gate[gw] = 1.0f / (1.0f + expf(-x));
  }
}

// ---------------- sequential EMA scan over T (parallel over B*D) ----------------

__global__ __launch_bounds__(256) void scan_kernel(
    const u16* __restrict__ vb, const float* __restrict__ gate,
    const float* __restrict__ vstate, const float* __restrict__ log_alpha,
    u16* __restrict__ ret, float* __restrict__ fstate)
{
  const int gid = blockIdx.x * 256 + threadIdx.x;   // b*1024 + h*128 + d
  const int b = gid >> 10;
  const int c = gid & 1023;
  const int h = c >> 7;
  const float alpha = 1.0f / (1.0f + expf(-log_alpha[h]));
  const float oma = 1.0f - alpha;
  float state = vstate[gid];
  const u16* vp = vb + (size_t)b * D_DIM + c;
  u16* rp = ret + (size_t)b * D_DIM + c;
  const float* gp = gate + b * H_DIM + h;
#pragma unroll 4
  for (int t = 0; t < T_DIM; ++t) {
    const float v = bf2f(vp[(size_t)t * (B_DIM * D_DIM)]);
    const float g = gp[(size_t)t * (B_DIM * H_DIM)];
    state = alpha * v + oma * state;
    rp[(size_t)t * (B_DIM * D_DIM)] = f2bf(g * state);
  }
  fstate[gid] = state;
}

// ---------------- launch ----------------

extern "C" void kernel_launch(void* const* d_in, const int* in_sizes, int n_in,
                              void* d_out, int out_size, void* d_ws, size_t ws_size,
                              hipStream_t stream) {
  const float* x_real      = (const float*)d_in[0];
  const float* x_imag      = (const float*)d_in[1];
  const float* value_state = (const float*)d_in[2];
  // d_in[3] = t (unused by the math)
  const float* Wr_in  = (const float*)d_in[4];
  const float* Wi_in  = (const float*)d_in[5];
  const float* br_in  = (const float*)d_in[6];
  const float* bi_in  = (const float*)d_in[7];
  const float* ln_g   = (const float*)d_in[8];
  const float* ln_b   = (const float*)d_in[9];
  const float* W_qkv  = (const float*)d_in[10];
  const float* log_alpha = (const float*)d_in[11];
  const float* Wr_out = (const float*)d_in[12];
  const float* Wi_out = (const float*)d_in[13];

  float* out_real = (float*)d_out;
  float* out_imag = out_real + (size_t)MROWS * D_DIM;
  float* fstate   = out_imag + (size_t)MROWS * D_DIM;

  // Scratch carved out of d_out (regions dead until the final out-proj GEMM):
  u16* R0a = (u16*)d_out;                                        // xr -> Q -> (dead)
  u16* xc  = (u16*)((char*)d_out + (size_t)MROWS * D_DIM * 2);   // proj out, LN'd
  u16* Vb  = (u16*)out_imag;                                     // V

  // d_ws buffers (~79 MB)
  char* ws = (char*)d_ws;
  size_t off = 0;
  auto alloc = [&](size_t bytes) { void* p = ws + off; off += (bytes + 255) & ~(size_t)255; return p; };
  u16*   Wc    = (u16*)alloc((size_t)1024 * 2048 * 2);
  u16*   Wqkvb = (u16*)alloc((size_t)3072 * 1024 * 2);
  u16*   Wob   = (u16*)alloc((size_t)2048 * 1024 * 2);   // [Wr_out; Wi_out]
  float* bc    = (float*)alloc((size_t)D_DIM * 4);
  u16*   R0b   = (u16*)alloc((size_t)MROWS * D_DIM * 2); // xi -> K -> retrieved
  float* gate  = (float*)alloc((size_t)MROWS * H_DIM * 4);

  // allow 128 KB dynamic LDS for the GEMM instantiations (host-side, capture-safe)
  const int LDSB = 131072;
  hipFuncSetAttribute((const void*)gemm256_kernel<1>, hipFuncAttributeMaxDynamicSharedMemorySize, LDSB);
  hipFuncSetAttribute((const void*)gemm256_kernel<2>, hipFuncAttributeMaxDynamicSharedMemorySize, LDSB);
  hipFuncSetAttribute((const void*)gemm256_kernel<3>, hipFuncAttributeMaxDynamicSharedMemorySize, LDSB);

  // --- weight prep ---
  prep_wc_kernel<<<(1024 * 2048) / 256, 256, 0, stream>>>(Wr_in, Wi_in, Wc);
  prep_bc_kernel<<<4, 256, 0, stream>>>(br_in, bi_in, bc);
  cast_bf16_kernel<<<1536, 256, 0, stream>>>(W_qkv, Wqkvb, (size_t)3072 * 1024 / 8);
  cast_bf16_kernel<<<512, 256, 0, stream>>>(Wr_out, Wob, (size_t)1024 * 1024 / 8);
  cast_bf16_kernel<<<512, 256, 0, stream>>>(Wi_out, Wob + (size_t)1024 * 1024, (size_t)1024 * 1024 / 8);
  // --- activation casts ---
  cast_bf16_kernel<<<4096, 256, 0, stream>>>(x_real, R0a, (size_t)MROWS * D_DIM / 8);
  cast_bf16_kernel<<<4096, 256, 0, stream>>>(x_imag, R0b, (size_t)MROWS * D_DIM / 8);

  // input proj: xc_pre = [xr|xi] @ Wc^T + bc   (K=2048, split at 1024) -> xc
  gemm256_kernel<1><<<dim3(128 * 4), 512, LDSB, stream>>>(
      R0a, R0b, 1024, 1024, Wc, 2048, bc, xc, nullptr, nullptr, 1024, 2048, 4);
  // LayerNorm in place
  ln_kernel<<<MROWS, 256, 0, stream>>>(xc, ln_g, ln_b);
  // QKV in ONE GEMM (N=3072): Q -> R0a, K -> R0b, V -> Vb
  gemm256_kernel<3><<<dim3(128 * 12), 512, LDSB, stream>>>(
      xc, xc, 1024, 1024, Wqkvb, 1024, nullptr, R0a, R0b, Vb, 1024, 1024, 12);
  // gate from Q,K
  gate_kernel<<<(MROWS * H_DIM) / 4, 256, 0, stream>>>(R0a, R0b, gate);
  // EMA scan: retrieved -> R0b (overwrites dead K), final_state -> d_out tail
  scan_kernel<<<(B_DIM * D_DIM) / 256, 256, 0, stream>>>(Vb, gate, value_state, log_alpha, R0b, fstate);
  // output projections in ONE GEMM (N=2048, f32 out): -> out_real | out_imag
  gemm256_kernel<2><<<dim3(128 * 8), 512, LDSB, stream>>>(
      R0b, R0b, 1024, 1024, Wob, 1024, nullptr, out_real, out_imag, nullptr, 1024, 1024, 8);
}

// Round 4
// 764.354 us; speedup vs baseline: 1.3522x; 1.0429x over previous
//
#include <hip/hip_runtime.h>
#include <stdint.h>

#define T_DIM 512
#define B_DIM 64
#define D_DIM 1024
#define H_DIM 8
#define DH_DIM 128
#define MROWS (T_DIM * B_DIM)   // 32768 rows across all timesteps

typedef unsigned short u16;
typedef __attribute__((ext_vector_type(8))) __bf16 bf16x8;
typedef __attribute__((ext_vector_type(4))) float f32x4;

__device__ __forceinline__ u16 f2bf(float f) {
  union { float f; uint32_t u; } v; v.f = f;
  uint32_t u = v.u;
  u += 0x7fffu + ((u >> 16) & 1u);   // RNE
  return (u16)(u >> 16);
}
__device__ __forceinline__ float bf2f(u16 h) {
  union { uint32_t u; float f; } v; v.u = ((uint32_t)h) << 16;
  return v.f;
}

__device__ __forceinline__ void gload16(const void* g, void* l) {
  __builtin_amdgcn_global_load_lds(
      (const __attribute__((address_space(1))) uint32_t*)g,
      (__attribute__((address_space(3))) uint32_t*)l, 16, 0, 0);
}

// ---------------- elementwise prep ----------------

__global__ void cast_bf16_kernel(const float* __restrict__ in, u16* __restrict__ out, size_t n8) {
  size_t i = (size_t)blockIdx.x * blockDim.x + threadIdx.x;
  const size_t stride = (size_t)gridDim.x * blockDim.x;
  for (; i < n8; i += stride) {
    const float4 a = ((const float4*)in)[i * 2];
    const float4 b = ((const float4*)in)[i * 2 + 1];
    union { u16 h[8]; uint4 u; } o;
    o.h[0] = f2bf(a.x); o.h[1] = f2bf(a.y); o.h[2] = f2bf(a.z); o.h[3] = f2bf(a.w);
    o.h[4] = f2bf(b.x); o.h[5] = f2bf(b.y); o.h[6] = f2bf(b.z); o.h[7] = f2bf(b.w);
    ((uint4*)out)[i] = o.u;
  }
}

// Wc[n][k] = Wr[n][k]+Wi[n][k] (k<1024)  |  Wr[n][k-1024]-Wi[n][k-1024]  -> (1024, 2048) bf16
__global__ void prep_wc_kernel(const float* __restrict__ Wr, const float* __restrict__ Wi,
                               u16* __restrict__ Wc) {
  const int idx = blockIdx.x * 256 + threadIdx.x;  // over 1024*2048
  const int n = idx >> 11;
  const int k = idx & 2047;
  const int kk = k & 1023;
  const float a = Wr[n * 1024 + kk], b = Wi[n * 1024 + kk];
  Wc[idx] = f2bf(k < 1024 ? a + b : a - b);
}

__global__ void prep_bc_kernel(const float* __restrict__ br, const float* __restrict__ bi,
                               float* __restrict__ bc) {
  const int i = blockIdx.x * 256 + threadIdx.x;
  if (i < D_DIM) bc[i] = br[i] + bi[i];
}

// ---------------- 256x256 8-phase bf16 MFMA GEMM: C = A @ W^T (+bias) ----------------
// 512 threads = 8 waves (2M x 4N), per-wave C 128x64, BK=64, 2 K-tiles per iter.
// LDS 128 KB: [buf:2][ Ak0 | Ak1 | Bk0 | Bk1 ], each half-tile 8192 u16 = 16 KB
//   (A half = 256 rows x 32 k; B half = 256 n-rows x 32 k; [row][4 punits][8 bf16]).
// Swizzle: punit stored = logical_u ^ (r&3) ^ ((r>>2)&3); applied on the GLOBAL source
// (linear LDS dest, rule #21); read side collapses to lane-constant puA -> <=2-way conflicts.
// Phase (ks,qm): read 4 A-frags (+4 B-frags when qm==0, held in regs for qm==1),
// stage one half-tile (2 gload16), barrier, lgkmcnt(0), setprio(1), 16 MFMA, setprio(0), barrier.
// Stage rotation per iter (tiles u=2i buf0, v=2i+1 buf1):
//   ph1:Ak1(v)->b1  ph2:Bk1(v)->b1  ph3:Ak0(u+2)->b0  ph4:Bk0(u+2)->b0
//   ph5:Ak1(u+2)->b0 ph6:Bk1(u+2)->b0 ph7:Ak0(v+2)->b1 ph8:Bk0(v+2)->b1
// vmcnt(4) ONLY before ph4's and ph8's end-barrier (counted wait, never 0 in loop).

template <int BUF, int KS, int QM, bool RB, bool VMW, typename F>
__device__ __forceinline__ void phase_op(const u16* lds, f32x4 (&acc)[8][4],
                                         bf16x8 (&bfr)[4], int wr, int wc, int la,
                                         int puA, F&& stage) {
  const u16* sA = lds + BUF * 32768 + KS * 8192;
  bf16x8 afr[4];
#pragma unroll
  for (int j = 0; j < 4; ++j)
    afr[j] = *(const bf16x8*)(sA + (wr * 128 + QM * 64 + j * 16 + la) * 32 + puA);
  if (RB) {
    const u16* sB = lds + BUF * 32768 + 16384 + KS * 8192;
#pragma unroll
    for (int ni = 0; ni < 4; ++ni)
      bfr[ni] = *(const bf16x8*)(sB + (wc * 64 + ni * 16 + la) * 32 + puA);
  }
  stage();
  __builtin_amdgcn_sched_barrier(0);
  __builtin_amdgcn_s_barrier();
  asm volatile("s_waitcnt lgkmcnt(0)" ::: "memory");
  __builtin_amdgcn_sched_barrier(0);
  __builtin_amdgcn_s_setprio(1);
#pragma unroll
  for (int mi = 0; mi < 4; ++mi)
#pragma unroll
    for (int ni = 0; ni < 4; ++ni)
      acc[QM * 4 + mi][ni] =
          __builtin_amdgcn_mfma_f32_16x16x32_bf16(afr[mi], bfr[ni], acc[QM * 4 + mi][ni], 0, 0, 0);
  __builtin_amdgcn_s_setprio(0);
  __builtin_amdgcn_sched_barrier(0);
  if (VMW) asm volatile("s_waitcnt vmcnt(4)" ::: "memory");
  __builtin_amdgcn_s_barrier();
  __builtin_amdgcn_sched_barrier(0);
}

template <int EPI>
__global__ __launch_bounds__(512, 2) void gemm256_kernel(
    const u16* __restrict__ A0, const u16* __restrict__ A1, int kSplit, int lda,
    const u16* __restrict__ Bw, int ldb,
    const float* __restrict__ bias,
    void* __restrict__ C0, void* __restrict__ C1, void* __restrict__ C2,
    int ldc, int K, int nColBlk)
{
  extern __shared__ u16 lds[];   // 65536 u16 = 128 KB
  const int tid  = threadIdx.x;
  const int lane = tid & 63;
  const int w    = tid >> 6;
  const int wr   = w >> 2;       // 0..1
  const int wc   = w & 3;        // 0..3

  // XCD-contiguous swizzle: bid%8 -> XCD, 16 row-panels per XCD, row-major within band
  const int bid   = blockIdx.x;
  const int xcd   = bid & 7;
  const int local = bid >> 3;
  const int rowL  = local / nColBlk;
  const int colB  = local - rowL * nColBlk;
  const size_t rowBase = (size_t)(xcd * 16 + rowL) * 256;
  const size_t colBase = (size_t)colB * 256;

  f32x4 acc[8][4];
#pragma unroll
  for (int i = 0; i < 8; ++i)
#pragma unroll
    for (int j = 0; j < 4; ++j) acc[i][j] = (f32x4){0.f, 0.f, 0.f, 0.f};

  const int NT = K >> 6;
  const int la = lane & 15;
  const int g  = lane >> 4;
  const int puA = ((g ^ (la & 3) ^ ((la >> 2) & 3)) << 3);   // lane-constant read punit (u16 units)

  // stage one half-tile (2 gload16/thread), linear LDS dest + inverse-swizzled global source
  auto stageA = [&](int buf, int ks, int t) {
    if (t >= NT) return;
    const int kb = t * 64;
    const u16* Ab; int kc;
    if (kb < kSplit) { Ab = A0; kc = kb; } else { Ab = A1; kc = kb - kSplit; }
    u16* dst = lds + buf * 32768 + ks * 8192;
#pragma unroll
    for (int i2 = 0; i2 < 2; ++i2) {
      const int l = i2 * 512 + tid, r = l >> 2, p = l & 3;
      const int lu = p ^ (r & 3) ^ ((r >> 2) & 3);
      gload16(Ab + (rowBase + r) * (size_t)lda + kc + ks * 32 + lu * 8, dst + l * 8);
    }
  };
  auto stageB = [&](int buf, int ks, int t) {
    if (t >= NT) return;
    const int kb = t * 64;
    u16* dst = lds + buf * 32768 + 16384 + ks * 8192;
#pragma unroll
    for (int i2 = 0; i2 < 2; ++i2) {
      const int l = i2 * 512 + tid, r = l >> 2, p = l & 3;
      const int lu = p ^ (r & 3) ^ ((r >> 2) & 3);
      gload16(Bw + (colBase + r) * (size_t)ldb + kb + ks * 32 + lu * 8, dst + l * 8);
    }
  };

  // prologue: tile0 complete + tile1 k0-halves  (12 loads in flight)
  stageA(0, 0, 0); stageB(0, 0, 0); stageA(0, 1, 0); stageB(0, 1, 0);
  stageA(1, 0, 1); stageB(1, 0, 1);
  asm volatile("s_waitcnt vmcnt(4)" ::: "memory");   // tile0 resident; tile1.k0 may fly
  __builtin_amdgcn_sched_barrier(0);
  __builtin_amdgcn_s_barrier();
  __builtin_amdgcn_sched_barrier(0);

  bf16x8 bfr[4];
  const int NIT = NT >> 1;
  for (int i = 0; i < NIT; ++i) {
    const int u = 2 * i, v = 2 * i + 1;
    phase_op<0, 0, 0, true , false>(lds, acc, bfr, wr, wc, la, puA, [&] { stageA(1, 1, v); });
    phase_op<0, 0, 1, false, false>(lds, acc, bfr, wr, wc, la, puA, [&] { stageB(1, 1, v); });
    phase_op<0, 1, 0, true , false>(lds, acc, bfr, wr, wc, la, puA, [&] { stageA(0, 0, u + 2); });
    phase_op<0, 1, 1, false, true >(lds, acc, bfr, wr, wc, la, puA, [&] { stageB(0, 0, u + 2); });
    phase_op<1, 0, 0, true , false>(lds, acc, bfr, wr, wc, la, puA, [&] { stageA(0, 1, u + 2); });
    phase_op<1, 0, 1, false, false>(lds, acc, bfr, wr, wc, la, puA, [&] { stageB(0, 1, u + 2); });
    phase_op<1, 1, 0, true , false>(lds, acc, bfr, wr, wc, la, puA, [&] { stageA(1, 0, v + 2); });
    phase_op<1, 1, 1, false, true >(lds, acc, bfr, wr, wc, la, puA, [&] { stageB(1, 0, v + 2); });
  }

  // epilogue: segment-select output buffer (colBase multiple of 256 -> block-uniform segment)
  const int seg = (int)(colBase >> 10);
  const size_t colSeg = colBase & 1023;
  void* Cout;
  if (EPI == 3)      Cout = (seg == 0) ? C0 : (seg == 1) ? C1 : C2;
  else if (EPI == 2) Cout = (seg == 0) ? C0 : C1;
  else               Cout = C0;

#pragma unroll
  for (int mi = 0; mi < 8; ++mi)
#pragma unroll
    for (int ni = 0; ni < 4; ++ni) {
      const int cn = wc * 64 + ni * 16 + la;
      const float badd = (EPI == 1) ? bias[colBase + cn] : 0.0f;
      const size_t col = colSeg + cn;
#pragma unroll
      for (int r = 0; r < 4; ++r) {
        const size_t row = rowBase + wr * 128 + mi * 16 + (lane >> 4) * 4 + r;
        const float v = acc[mi][ni][r] + badd;
        if (EPI == 2) ((float*)Cout)[row * (size_t)ldc + col] = v;
        else          ((u16*)Cout)[row * (size_t)ldc + col] = f2bf(v);
      }
    }
}

// ---------------- LayerNorm (in-place on bf16 rows) ----------------

__global__ __launch_bounds__(256) void ln_kernel(u16* __restrict__ xc,
    const float* __restrict__ gamma, const float* __restrict__ beta)
{
  const size_t row = blockIdx.x;
  u16* p = xc + row * D_DIM;
  const int tid = threadIdx.x;
  const int c = tid * 4;
  const uint2 raw = *(const uint2*)(p + c);
  const float v0 = bf2f((u16)(raw.x & 0xffff)), v1 = bf2f((u16)(raw.x >> 16));
  const float v2 = bf2f((u16)(raw.y & 0xffff)), v3 = bf2f((u16)(raw.y >> 16));
  float s = v0 + v1 + v2 + v3;
  float q = v0 * v0 + v1 * v1 + v2 * v2 + v3 * v3;
#pragma unroll
  for (int o = 32; o > 0; o >>= 1) { s += __shfl_xor(s, o); q += __shfl_xor(q, o); }
  __shared__ float red[8];
  if ((tid & 63) == 0) { red[(tid >> 6) * 2] = s; red[(tid >> 6) * 2 + 1] = q; }
  __syncthreads();
  s = red[0] + red[2] + red[4] + red[6];
  q = red[1] + red[3] + red[5] + red[7];
  const float mu = s * (1.0f / D_DIM);
  const float var = q * (1.0f / D_DIM) - mu * mu;
  const float rstd = 1.0f / sqrtf(var + 1e-5f);
  const float y0 = (v0 - mu) * rstd * gamma[c] + beta[c];
  const float y1 = (v1 - mu) * rstd * gamma[c + 1] + beta[c + 1];
  const float y2 = (v2 - mu) * rstd * gamma[c + 2] + beta[c + 2];
  const float y3 = (v3 - mu) * rstd * gamma[c + 3] + beta[c + 3];
  const uint32_t o0 = (uint32_t)f2bf(y0) | ((uint32_t)f2bf(y1) << 16);
  const uint32_t o1 = (uint32_t)f2bf(y2) | ((uint32_t)f2bf(y3) << 16);
  *(uint2*)(p + c) = make_uint2(o0, o1);
}

// ---------------- gate[row,h] = sigmoid(q.k / sqrt(DH)) — one wave per (row,h) ----------------

__global__ __launch_bounds__(256) void gate_kernel(
    const u16* __restrict__ Q, const u16* __restrict__ Kb, float* __restrict__ gate)
{
  const int gw = blockIdx.x * 4 + (threadIdx.x >> 6);   // wave id: row*8 + h
  const int lane = threadIdx.x & 63;
  const size_t row = (size_t)(gw >> 3);
  const int h = gw & 7;
  const size_t off = row * D_DIM + h * DH_DIM + lane * 2;
  const uint32_t qr = *(const uint32_t*)(Q + off);
  const uint32_t kr = *(const uint32_t*)(Kb + off);
  float d = bf2f((u16)(qr & 0xffff)) * bf2f((u16)(kr & 0xffff))
          + bf2f((u16)(qr >> 16))    * bf2f((u16)(kr >> 16));
#pragma unroll
  for (int o = 32; o > 0; o >>= 1) d += __shfl_xor(d, o);
  if (lane == 0) {
    const float x = d * 0.08838834764831845f;  // 1/sqrt(128)
    gate[gw] = 1.0f / (1.0f + expf(-x));
  }
}

// ---------------- sequential EMA scan over T (parallel over B*D) ----------------

__global__ __launch_bounds__(256) void scan_kernel(
    const u16* __restrict__ vb, const float* __restrict__ gate,
    const float* __restrict__ vstate, const float* __restrict__ log_alpha,
    u16* __restrict__ ret, float* __restrict__ fstate)
{
  const int gid = blockIdx.x * 256 + threadIdx.x;   // b*1024 + h*128 + d
  const int b = gid >> 10;
  const int c = gid & 1023;
  const int h = c >> 7;
  const float alpha = 1.0f / (1.0f + expf(-log_alpha[h]));
  const float oma = 1.0f - alpha;
  float state = vstate[gid];
  const u16* vp = vb + (size_t)b * D_DIM + c;
  u16* rp = ret + (size_t)b * D_DIM + c;
  const float* gp = gate + b * H_DIM + h;
#pragma unroll 4
  for (int t = 0; t < T_DIM; ++t) {
    const float v = bf2f(vp[(size_t)t * (B_DIM * D_DIM)]);
    const float g = gp[(size_t)t * (B_DIM * H_DIM)];
    state = alpha * v + oma * state;
    rp[(size_t)t * (B_DIM * D_DIM)] = f2bf(g * state);
  }
  fstate[gid] = state;
}

// ---------------- launch ----------------

extern "C" void kernel_launch(void* const* d_in, const int* in_sizes, int n_in,
                              void* d_out, int out_size, void* d_ws, size_t ws_size,
                              hipStream_t stream) {
  const float* x_real      = (const float*)d_in[0];
  const float* x_imag      = (const float*)d_in[1];
  const float* value_state = (const float*)d_in[2];
  // d_in[3] = t (unused by the math)
  const float* Wr_in  = (const float*)d_in[4];
  const float* Wi_in  = (const float*)d_in[5];
  const float* br_in  = (const float*)d_in[6];
  const float* bi_in  = (const float*)d_in[7];
  const float* ln_g   = (const float*)d_in[8];
  const float* ln_b   = (const float*)d_in[9];
  const float* W_qkv  = (const float*)d_in[10];
  const float* log_alpha = (const float*)d_in[11];
  const float* Wr_out = (const float*)d_in[12];
  const float* Wi_out = (const float*)d_in[13];

  float* out_real = (float*)d_out;
  float* out_imag = out_real + (size_t)MROWS * D_DIM;
  float* fstate   = out_imag + (size_t)MROWS * D_DIM;

  // Scratch carved out of d_out (regions dead until the final out-proj GEMM):
  u16* R0a = (u16*)d_out;                                        // xr -> Q -> (dead)
  u16* xc  = (u16*)((char*)d_out + (size_t)MROWS * D_DIM * 2);   // proj out, LN'd
  u16* Vb  = (u16*)out_imag;                                     // V

  // d_ws buffers (~79 MB)
  char* ws = (char*)d_ws;
  size_t off = 0;
  auto alloc = [&](size_t bytes) { void* p = ws + off; off += (bytes + 255) & ~(size_t)255; return p; };
  u16*   Wc    = (u16*)alloc((size_t)1024 * 2048 * 2);
  u16*   Wqkvb = (u16*)alloc((size_t)3072 * 1024 * 2);
  u16*   Wob   = (u16*)alloc((size_t)2048 * 1024 * 2);   // [Wr_out; Wi_out]
  float* bc    = (float*)alloc((size_t)D_DIM * 4);
  u16*   R0b   = (u16*)alloc((size_t)MROWS * D_DIM * 2); // xi -> K -> retrieved
  float* gate  = (float*)alloc((size_t)MROWS * H_DIM * 4);

  // allow 128 KB dynamic LDS for the GEMM instantiations (host-side, capture-safe)
  const int LDSB = 131072;
  hipFuncSetAttribute((const void*)gemm256_kernel<1>, hipFuncAttributeMaxDynamicSharedMemorySize, LDSB);
  hipFuncSetAttribute((const void*)gemm256_kernel<2>, hipFuncAttributeMaxDynamicSharedMemorySize, LDSB);
  hipFuncSetAttribute((const void*)gemm256_kernel<3>, hipFuncAttributeMaxDynamicSharedMemorySize, LDSB);

  // --- weight prep ---
  prep_wc_kernel<<<(1024 * 2048) / 256, 256, 0, stream>>>(Wr_in, Wi_in, Wc);
  prep_bc_kernel<<<4, 256, 0, stream>>>(br_in, bi_in, bc);
  cast_bf16_kernel<<<1536, 256, 0, stream>>>(W_qkv, Wqkvb, (size_t)3072 * 1024 / 8);
  cast_bf16_kernel<<<512, 256, 0, stream>>>(Wr_out, Wob, (size_t)1024 * 1024 / 8);
  cast_bf16_kernel<<<512, 256, 0, stream>>>(Wi_out, Wob + (size_t)1024 * 1024, (size_t)1024 * 1024 / 8);
  // --- activation casts ---
  cast_bf16_kernel<<<4096, 256, 0, stream>>>(x_real, R0a, (size_t)MROWS * D_DIM / 8);
  cast_bf16_kernel<<<4096, 256, 0, stream>>>(x_imag, R0b, (size_t)MROWS * D_DIM / 8);

  // input proj: xc_pre = [xr|xi] @ Wc^T + bc   (K=2048, split at 1024) -> xc
  gemm256_kernel<1><<<dim3(128 * 4), 512, LDSB, stream>>>(
      R0a, R0b, 1024, 1024, Wc, 2048, bc, xc, nullptr, nullptr, 1024, 2048, 4);
  // LayerNorm in place
  ln_kernel<<<MROWS, 256, 0, stream>>>(xc, ln_g, ln_b);
  // QKV in ONE GEMM (N=3072): Q -> R0a, K -> R0b, V -> Vb
  gemm256_kernel<3><<<dim3(128 * 12), 512, LDSB, stream>>>(
      xc, xc, 1024, 1024, Wqkvb, 1024, nullptr, R0a, R0b, Vb, 1024, 1024, 12);
  // gate from Q,K
  gate_kernel<<<(MROWS * H_DIM) / 4, 256, 0, stream>>>(R0a, R0b, gate);
  // EMA scan: retrieved -> R0b (overwrites dead K), final_state -> d_out tail
  scan_kernel<<<(B_DIM * D_DIM) / 256, 256, 0, stream>>>(Vb, gate, value_state, log_alpha, R0b, fstate);
  // output projections in ONE GEMM (N=2048, f32 out): -> out_real | out_imag
  gemm256_kernel<2><<<dim3(128 * 8), 512, LDSB, stream>>>(
      R0b, R0b, 1024, 1024, Wob, 1024, nullptr, out_real, out_imag, nullptr, 1024, 1024, 8);
}

// Round 5
// 752.059 us; speedup vs baseline: 1.3743x; 1.0163x over previous
//
#include <hip/hip_runtime.h>
#include <stdint.h>

#define T_DIM 512
#define B_DIM 64
#define D_DIM 1024
#define H_DIM 8
#define DH_DIM 128
#define MROWS (T_DIM * B_DIM)   // 32768 rows across all timesteps

typedef unsigned short u16;
typedef __attribute__((ext_vector_type(8))) __bf16 bf16x8;
typedef __attribute__((ext_vector_type(4))) float f32x4;
typedef __attribute__((ext_vector_type(16))) float f32x16;

__device__ __forceinline__ u16 f2bf(float f) {
  union { float f; uint32_t u; } v; v.f = f;
  uint32_t u = v.u;
  u += 0x7fffu + ((u >> 16) & 1u);   // RNE
  return (u16)(u >> 16);
}
__device__ __forceinline__ float bf2f(u16 h) {
  union { uint32_t u; float f; } v; v.u = ((uint32_t)h) << 16;
  return v.f;
}

__device__ __forceinline__ void gload16(const void* g, void* l) {
  __builtin_amdgcn_global_load_lds(
      (const __attribute__((address_space(1))) uint32_t*)g,
      (__attribute__((address_space(3))) uint32_t*)l, 16, 0, 0);
}

// ---------------- elementwise prep ----------------

__global__ void cast_bf16_kernel(const float* __restrict__ in, u16* __restrict__ out, size_t n8) {
  size_t i = (size_t)blockIdx.x * blockDim.x + threadIdx.x;
  const size_t stride = (size_t)gridDim.x * blockDim.x;
  for (; i < n8; i += stride) {
    const float4 a = ((const float4*)in)[i * 2];
    const float4 b = ((const float4*)in)[i * 2 + 1];
    union { u16 h[8]; uint4 u; } o;
    o.h[0] = f2bf(a.x); o.h[1] = f2bf(a.y); o.h[2] = f2bf(a.z); o.h[3] = f2bf(a.w);
    o.h[4] = f2bf(b.x); o.h[5] = f2bf(b.y); o.h[6] = f2bf(b.z); o.h[7] = f2bf(b.w);
    ((uint4*)out)[i] = o.u;
  }
}

// Wc[n][k] = Wr[n][k]+Wi[n][k] (k<1024)  |  Wr[n][k-1024]-Wi[n][k-1024]  -> (1024, 2048) bf16
__global__ void prep_wc_kernel(const float* __restrict__ Wr, const float* __restrict__ Wi,
                               u16* __restrict__ Wc) {
  const int idx = blockIdx.x * 256 + threadIdx.x;  // over 1024*2048
  const int n = idx >> 11;
  const int k = idx & 2047;
  const int kk = k & 1023;
  const float a = Wr[n * 1024 + kk], b = Wi[n * 1024 + kk];
  Wc[idx] = f2bf(k < 1024 ? a + b : a - b);
}

__global__ void prep_bc_kernel(const float* __restrict__ br, const float* __restrict__ bi,
                               float* __restrict__ bc) {
  const int i = blockIdx.x * 256 + threadIdx.x;
  if (i < D_DIM) bc[i] = br[i] + bi[i];
}

// ---------------- 256x256 8-phase bf16 MFMA GEMM (32x32x16): C = A @ W^T (+bias) ----------------
// 512 threads = 8 waves (2M x 4N), per-wave C 128x64 = 4x2 frags of 32x32, BK=64, 2 K-tiles/iter.
// LDS 128 KB: [buf:2][ Ak0 | Ak1 | Bk0 | Bk1 ], half-tile 8192 u16 = 16 KB ([row][4 punits][8]).
// Swizzle: punit stored = logical_u ^ (r&3) ^ ((r>>2)&3), applied on the GLOBAL source
// (linear LDS dest, rule #21); read punit = (g2 ^ f(lane)) ^ (kk*2) -> lane-constant base,
// ^16 u16 for kk=1. Verified: 8-lane groups hit all 32 banks exactly once.
// Phase (ks,qm=m-half): read 4 A-frags (+4 B-frags when qm==0, held for qm==1),
// stage one half-tile, barrier, lgkmcnt(0), setprio(1), 8 MFMA_32x32x16, setprio(0), barrier.
// Stage rotation per iter (tiles u=2i buf0, v=2i+1 buf1):
//   ph1:Ak1(v)->b1  ph2:Bk1(v)->b1  ph3:Ak0(u+2)->b0  ph4:Bk0(u+2)->b0
//   ph5:Ak1(u+2)->b0 ph6:Bk1(u+2)->b0 ph7:Ak0(v+2)->b1 ph8:Bk0(v+2)->b1
// vmcnt(4) ONLY before ph4's and ph8's end-barrier (counted wait, never 0 in loop).

template <int BUF, int KS, int QM, bool RB, bool VMW, typename F>
__device__ __forceinline__ void phase_op(const u16* lds, f32x16 (&acc)[4][2],
                                         bf16x8 (&bfr)[2][2], int wr, int wc, int la32,
                                         int puA, F&& stage) {
  const u16* sA = lds + BUF * 32768 + KS * 8192;
  bf16x8 afr[2][2];
#pragma unroll
  for (int mf = 0; mf < 2; ++mf)
#pragma unroll
    for (int kk = 0; kk < 2; ++kk)
      afr[mf][kk] = *(const bf16x8*)(sA + (wr * 128 + QM * 64 + mf * 32 + la32) * 32 + (puA ^ (kk << 4)));
  if (RB) {
    const u16* sB = lds + BUF * 32768 + 16384 + KS * 8192;
#pragma unroll
    for (int nf = 0; nf < 2; ++nf)
#pragma unroll
      for (int kk = 0; kk < 2; ++kk)
        bfr[nf][kk] = *(const bf16x8*)(sB + (wc * 64 + nf * 32 + la32) * 32 + (puA ^ (kk << 4)));
  }
  stage();
  __builtin_amdgcn_sched_barrier(0);
  __builtin_amdgcn_s_barrier();
  asm volatile("s_waitcnt lgkmcnt(0)" ::: "memory");
  __builtin_amdgcn_sched_barrier(0);
  __builtin_amdgcn_s_setprio(1);
#pragma unroll
  for (int kk = 0; kk < 2; ++kk)
#pragma unroll
    for (int mf = 0; mf < 2; ++mf)
#pragma unroll
      for (int nf = 0; nf < 2; ++nf)
        acc[QM * 2 + mf][nf] =
            __builtin_amdgcn_mfma_f32_32x32x16_bf16(afr[mf][kk], bfr[nf][kk], acc[QM * 2 + mf][nf], 0, 0, 0);
  __builtin_amdgcn_s_setprio(0);
  __builtin_amdgcn_sched_barrier(0);
  if (VMW) asm volatile("s_waitcnt vmcnt(4)" ::: "memory");
  __builtin_amdgcn_s_barrier();
  __builtin_amdgcn_sched_barrier(0);
}

template <int EPI>
__global__ __launch_bounds__(512, 2) void gemm256_kernel(
    const u16* __restrict__ A0, const u16* __restrict__ A1, int kSplit, int lda,
    const u16* __restrict__ Bw, int ldb,
    const float* __restrict__ bias,
    void* __restrict__ C0, void* __restrict__ C1, void* __restrict__ C2,
    int ldc, int K, int nColBlk)
{
  extern __shared__ u16 lds[];   // 65536 u16 = 128 KB
  const int tid  = threadIdx.x;
  const int lane = tid & 63;
  const int w    = tid >> 6;
  const int wr   = w >> 2;       // 0..1
  const int wc   = w & 3;        // 0..3

  // XCD-contiguous swizzle: bid%8 -> XCD, 16 row-panels per XCD, row-major within band
  const int bid   = blockIdx.x;
  const int xcd   = bid & 7;
  const int local = bid >> 3;
  const int rowL  = local / nColBlk;
  const int colB  = local - rowL * nColBlk;
  const size_t rowBase = (size_t)(xcd * 16 + rowL) * 256;
  const size_t colBase = (size_t)colB * 256;

  f32x16 acc[4][2];
#pragma unroll
  for (int i = 0; i < 4; ++i)
#pragma unroll
    for (int j = 0; j < 2; ++j)
#pragma unroll
      for (int e = 0; e < 16; ++e) acc[i][j][e] = 0.f;

  const int NT = K >> 6;
  const int la32 = lane & 31;
  const int g2   = lane >> 5;
  const int f    = (la32 & 3) ^ ((la32 >> 2) & 3);
  const int puA  = ((g2 ^ f) << 3);   // u16 units; kk=1 -> ^16

  // stage one half-tile (2 gload16/thread), linear LDS dest + inverse-swizzled global source
  auto stageA = [&](int buf, int ks, int t) {
    if (t >= NT) return;
    const int kb = t * 64;
    const u16* Ab; int kc;
    if (kb < kSplit) { Ab = A0; kc = kb; } else { Ab = A1; kc = kb - kSplit; }
    u16* dst = lds + buf * 32768 + ks * 8192;
#pragma unroll
    for (int i2 = 0; i2 < 2; ++i2) {
      const int l = i2 * 512 + tid, r = l >> 2, p = l & 3;
      const int lu = p ^ (r & 3) ^ ((r >> 2) & 3);
      gload16(Ab + (rowBase + r) * (size_t)lda + kc + ks * 32 + lu * 8, dst + l * 8);
    }
  };
  auto stageB = [&](int buf, int ks, int t) {
    if (t >= NT) return;
    const int kb = t * 64;
    u16* dst = lds + buf * 32768 + 16384 + ks * 8192;
#pragma unroll
    for (int i2 = 0; i2 < 2; ++i2) {
      const int l = i2 * 512 + tid, r = l >> 2, p = l & 3;
      const int lu = p ^ (r & 3) ^ ((r >> 2) & 3);
      gload16(Bw + (colBase + r) * (size_t)ldb + kb + ks * 32 + lu * 8, dst + l * 8);
    }
  };

  // prologue: tile0 complete + tile1 k0-halves  (12 loads in flight)
  stageA(0, 0, 0); stageB(0, 0, 0); stageA(0, 1, 0); stageB(0, 1, 0);
  stageA(1, 0, 1); stageB(1, 0, 1);
  asm volatile("s_waitcnt vmcnt(4)" ::: "memory");   // tile0 resident; tile1.k0 may fly
  __builtin_amdgcn_sched_barrier(0);
  __builtin_amdgcn_s_barrier();
  __builtin_amdgcn_sched_barrier(0);

  bf16x8 bfr[2][2];
  const int NIT = NT >> 1;
  for (int i = 0; i < NIT; ++i) {
    const int u = 2 * i, v = 2 * i + 1;
    phase_op<0, 0, 0, true , false>(lds, acc, bfr, wr, wc, la32, puA, [&] { stageA(1, 1, v); });
    phase_op<0, 0, 1, false, false>(lds, acc, bfr, wr, wc, la32, puA, [&] { stageB(1, 1, v); });
    phase_op<0, 1, 0, true , false>(lds, acc, bfr, wr, wc, la32, puA, [&] { stageA(0, 0, u + 2); });
    phase_op<0, 1, 1, false, true >(lds, acc, bfr, wr, wc, la32, puA, [&] { stageB(0, 0, u + 2); });
    phase_op<1, 0, 0, true , false>(lds, acc, bfr, wr, wc, la32, puA, [&] { stageA(0, 1, u + 2); });
    phase_op<1, 0, 1, false, false>(lds, acc, bfr, wr, wc, la32, puA, [&] { stageB(0, 1, u + 2); });
    phase_op<1, 1, 0, true , false>(lds, acc, bfr, wr, wc, la32, puA, [&] { stageA(1, 0, v + 2); });
    phase_op<1, 1, 1, false, true >(lds, acc, bfr, wr, wc, la32, puA, [&] { stageB(1, 0, v + 2); });
  }

  // epilogue: segment-select output buffer (colBase multiple of 256 -> block-uniform segment)
  const int seg = (int)(colBase >> 10);
  const size_t colSeg = colBase & 1023;
  void* Cout;
  if (EPI == 3)      Cout = (seg == 0) ? C0 : (seg == 1) ? C1 : C2;
  else if (EPI == 2) Cout = (seg == 0) ? C0 : C1;
  else               Cout = C0;

  // C/D layout (32x32x16, m74/m101): col = lane&31, row = (r&3) + 8*(r>>2) + 4*(lane>>5)
#pragma unroll
  for (int mi = 0; mi < 4; ++mi)
#pragma unroll
    for (int ni = 0; ni < 2; ++ni) {
      const int cn = wc * 64 + ni * 32 + la32;
      const float badd = (EPI == 1) ? bias[colBase + cn] : 0.0f;
      const size_t col = colSeg + cn;
#pragma unroll
      for (int r = 0; r < 16; ++r) {
        const size_t row = rowBase + wr * 128 + mi * 32 + (r & 3) + 8 * (r >> 2) + 4 * g2;
        const float v = acc[mi][ni][r] + badd;
        if (EPI == 2) ((float*)Cout)[row * (size_t)ldc + col] = v;
        else          ((u16*)Cout)[row * (size_t)ldc + col] = f2bf(v);
      }
    }
}

// ---------------- LayerNorm (in-place on bf16 rows) ----------------

__global__ __launch_bounds__(256) void ln_kernel(u16* __restrict__ xc,
    const float* __restrict__ gamma, const float* __restrict__ beta)
{
  const size_t row = blockIdx.x;
  u16* p = xc + row * D_DIM;
  const int tid = threadIdx.x;
  const int c = tid * 4;
  const uint2 raw = *(const uint2*)(p + c);
  const float v0 = bf2f((u16)(raw.x & 0xffff)), v1 = bf2f((u16)(raw.x >> 16));
  const float v2 = bf2f((u16)(raw.y & 0xffff)), v3 = bf2f((u16)(raw.y >> 16));
  float s = v0 + v1 + v2 + v3;
  float q = v0 * v0 + v1 * v1 + v2 * v2 + v3 * v3;
#pragma unroll
  for (int o = 32; o > 0; o >>= 1) { s += __shfl_xor(s, o); q += __shfl_xor(q, o); }
  __shared__ float red[8];
  if ((tid & 63) == 0) { red[(tid >> 6) * 2] = s; red[(tid >> 6) * 2 + 1] = q; }
  __syncthreads();
  s = red[0] + red[2] + red[4] + red[6];
  q = red[1] + red[3] + red[5] + red[7];
  const float mu = s * (1.0f / D_DIM);
  const float var = q * (1.0f / D_DIM) - mu * mu;
  const float rstd = 1.0f / sqrtf(var + 1e-5f);
  const float y0 = (v0 - mu) * rstd * gamma[c] + beta[c];
  const float y1 = (v1 - mu) * rstd * gamma[c + 1] + beta[c + 1];
  const float y2 = (v2 - mu) * rstd * gamma[c + 2] + beta[c + 2];
  const float y3 = (v3 - mu) * rstd * gamma[c + 3] + beta[c + 3];
  const uint32_t o0 = (uint32_t)f2bf(y0) | ((uint32_t)f2bf(y1) << 16);
  const uint32_t o1 = (uint32_t)f2bf(y2) | ((uint32_t)f2bf(y3) << 16);
  *(uint2*)(p + c) = make_uint2(o0, o1);
}

// ---------------- gate[row,h] = sigmoid(q.k / sqrt(DH)) — one wave per (row,h) ----------------

__global__ __launch_bounds__(256) void gate_kernel(
    const u16* __restrict__ Q, const u16* __restrict__ Kb, float* __restrict__ gate)
{
  const int gw = blockIdx.x * 4 + (threadIdx.x >> 6);   // wave id: row*8 + h
  const int lane = threadIdx.x & 63;
  const size_t row = (size_t)(gw >> 3);
  const int h = gw & 7;
  const size_t off = row * D_DIM + h * DH_DIM + lane * 2;
  const uint32_t qr = *(const uint32_t*)(Q + off);
  const uint32_t kr = *(const uint32_t*)(Kb + off);
  float d = bf2f((u16)(qr & 0xffff)) * bf2f((u16)(kr & 0xffff))
          + bf2f((u16)(qr >> 16))    * bf2f((u16)(kr >> 16));
#pragma unroll
  for (int o = 32; o > 0; o >>= 1) d += __shfl_xor(d, o);
  if (lane == 0) {
    const float x = d * 0.08838834764831845f;  // 1/sqrt(128)
    gate[gw] = 1.0f / (1.0f + expf(-x));
  }
}

// ---------------- sequential EMA scan over T (parallel over B*D) ----------------

__global__ __launch_bounds__(256) void scan_kernel(
    const u16* __restrict__ vb, const float* __restrict__ gate,
    const float* __restrict__ vstate, const float* __restrict__ log_alpha,
    u16* __restrict__ ret, float* __restrict__ fstate)
{
  const int gid = blockIdx.x * 256 + threadIdx.x;   // b*1024 + h*128 + d
  const int b = gid >> 10;
  const int c = gid & 1023;
  const int h = c >> 7;
  const float alpha = 1.0f / (1.0f + expf(-log_alpha[h]));
  const float oma = 1.0f - alpha;
  float state = vstate[gid];
  const u16* vp = vb + (size_t)b * D_DIM + c;
  u16* rp = ret + (size_t)b * D_DIM + c;
  const float* gp = gate + b * H_DIM + h;
#pragma unroll 4
  for (int t = 0; t < T_DIM; ++t) {
    const float v = bf2f(vp[(size_t)t * (B_DIM * D_DIM)]);
    const float g = gp[(size_t)t * (B_DIM * H_DIM)];
    state = alpha * v + oma * state;
    rp[(size_t)t * (B_DIM * D_DIM)] = f2bf(g * state);
  }
  fstate[gid] = state;
}

// ---------------- launch ----------------

extern "C" void kernel_launch(void* const* d_in, const int* in_sizes, int n_in,
                              void* d_out, int out_size, void* d_ws, size_t ws_size,
                              hipStream_t stream) {
  const float* x_real      = (const float*)d_in[0];
  const float* x_imag      = (const float*)d_in[1];
  const float* value_state = (const float*)d_in[2];
  // d_in[3] = t (unused by the math)
  const float* Wr_in  = (const float*)d_in[4];
  const float* Wi_in  = (const float*)d_in[5];
  const float* br_in  = (const float*)d_in[6];
  const float* bi_in  = (const float*)d_in[7];
  const float* ln_g   = (const float*)d_in[8];
  const float* ln_b   = (const float*)d_in[9];
  const float* W_qkv  = (const float*)d_in[10];
  const float* log_alpha = (const float*)d_in[11];
  const float* Wr_out = (const float*)d_in[12];
  const float* Wi_out = (const float*)d_in[13];

  float* out_real = (float*)d_out;
  float* out_imag = out_real + (size_t)MROWS * D_DIM;
  float* fstate   = out_imag + (size_t)MROWS * D_DIM;

  // Scratch carved out of d_out (regions dead until the final out-proj GEMM):
  u16* R0a = (u16*)d_out;                                        // xr -> Q -> (dead)
  u16* xc  = (u16*)((char*)d_out + (size_t)MROWS * D_DIM * 2);   // proj out, LN'd
  u16* Vb  = (u16*)out_imag;                                     // V

  // d_ws buffers (~79 MB)
  char* ws = (char*)d_ws;
  size_t off = 0;
  auto alloc = [&](size_t bytes) { void* p = ws + off; off += (bytes + 255) & ~(size_t)255; return p; };
  u16*   Wc    = (u16*)alloc((size_t)1024 * 2048 * 2);
  u16*   Wqkvb = (u16*)alloc((size_t)3072 * 1024 * 2);
  u16*   Wob   = (u16*)alloc((size_t)2048 * 1024 * 2);   // [Wr_out; Wi_out]
  float* bc    = (float*)alloc((size_t)D_DIM * 4);
  u16*   R0b   = (u16*)alloc((size_t)MROWS * D_DIM * 2); // xi -> K -> retrieved
  float* gate  = (float*)alloc((size_t)MROWS * H_DIM * 4);

  // allow 128 KB dynamic LDS for the GEMM instantiations (host-side, capture-safe)
  const int LDSB = 131072;
  hipFuncSetAttribute((const void*)gemm256_kernel<1>, hipFuncAttributeMaxDynamicSharedMemorySize, LDSB);
  hipFuncSetAttribute((const void*)gemm256_kernel<2>, hipFuncAttributeMaxDynamicSharedMemorySize, LDSB);
  hipFuncSetAttribute((const void*)gemm256_kernel<3>, hipFuncAttributeMaxDynamicSharedMemorySize, LDSB);

  // --- weight prep ---
  prep_wc_kernel<<<(1024 * 2048) / 256, 256, 0, stream>>>(Wr_in, Wi_in, Wc);
  prep_bc_kernel<<<4, 256, 0, stream>>>(br_in, bi_in, bc);
  cast_bf16_kernel<<<1536, 256, 0, stream>>>(W_qkv, Wqkvb, (size_t)3072 * 1024 / 8);
  cast_bf16_kernel<<<512, 256, 0, stream>>>(Wr_out, Wob, (size_t)1024 * 1024 / 8);
  cast_bf16_kernel<<<512, 256, 0, stream>>>(Wi_out, Wob + (size_t)1024 * 1024, (size_t)1024 * 1024 / 8);
  // --- activation casts ---
  cast_bf16_kernel<<<4096, 256, 0, stream>>>(x_real, R0a, (size_t)MROWS * D_DIM / 8);
  cast_bf16_kernel<<<4096, 256, 0, stream>>>(x_imag, R0b, (size_t)MROWS * D_DIM / 8);

  // input proj: xc_pre = [xr|xi] @ Wc^T + bc   (K=2048, split at 1024) -> xc
  gemm256_kernel<1><<<dim3(128 * 4), 512, LDSB, stream>>>(
      R0a, R0b, 1024, 1024, Wc, 2048, bc, xc, nullptr, nullptr, 1024, 2048, 4);
  // LayerNorm in place
  ln_kernel<<<MROWS, 256, 0, stream>>>(xc, ln_g, ln_b);
  // QKV in ONE GEMM (N=3072): Q -> R0a, K -> R0b, V -> Vb
  gemm256_kernel<3><<<dim3(128 * 12), 512, LDSB, stream>>>(
      xc, xc, 1024, 1024, Wqkvb, 1024, nullptr, R0a, R0b, Vb, 1024, 1024, 12);
  // gate from Q,K
  gate_kernel<<<(MROWS * H_DIM) / 4, 256, 0, stream>>>(R0a, R0b, gate);
  // EMA scan: retrieved -> R0b (overwrites dead K), final_state -> d_out tail
  scan_kernel<<<(B_DIM * D_DIM) / 256, 256, 0, stream>>>(Vb, gate, value_state, log_alpha, R0b, fstate);
  // output projections in ONE GEMM (N=2048, f32 out): -> out_real | out_imag
  gemm256_kernel<2><<<dim3(128 * 8), 512, LDSB, stream>>>(
      R0b, R0b, 1024, 1024, Wob, 1024, nullptr, out_real, out_imag, nullptr, 1024, 1024, 8);
}